// Round 13
// baseline (344.238 us; speedup 1.0000x reference)
//
#include <hip/hip_runtime.h>
#include <hip/hip_bf16.h>

#define HID 96
#define NGRAPHS 64
#define SENT 0xC3C3u   // 50115: sentinel row (zeroed) for CSR padding
#define NROWS 50116    // N + sentinel row
#define NPB 84         // nodes per gather block (4 waves x 21 subgroups)

typedef __attribute__((ext_vector_type(8))) short short8;
typedef __attribute__((ext_vector_type(4))) float floatx4;
typedef __attribute__((ext_vector_type(8))) unsigned short ushort8v;

__device__ __forceinline__ float bf16_to_f32(unsigned short u) {
    unsigned int v = ((unsigned int)u) << 16;
    return __builtin_bit_cast(float, v);
}
__device__ __forceinline__ unsigned short f32_to_bf16(float f) {
    unsigned int u = __builtin_bit_cast(unsigned int, f);
    u += 0x7fff + ((u >> 16) & 1);  // RNE
    return (unsigned short)(u >> 16);
}

// ------------------------------------------------------------------ init ----
__global__ __launch_bounds__(256) void init_kernel(
    int* __restrict__ deg, float* __restrict__ psum,
    unsigned short* __restrict__ bufA, unsigned short* __restrict__ bufB, int N) {
    int i = blockIdx.x * 256 + threadIdx.x;
    if (i < N) deg[i] = 0;
    if (i < NGRAPHS * HID + NGRAPHS) psum[i] = 0.0f;
    if (i < HID) {  // zero sentinel row in sliced layout
        size_t off = ((size_t)(i / 12) * NROWS + SENT) * 12 + (i % 12);
        bufA[off] = 0;
        bufB[off] = 0;
    }
}

// ---------------------------------------------------------------- degree ----
__global__ void deg_kernel(const int* __restrict__ dst, int* __restrict__ deg,
                           int n_edges) {
    int t = blockIdx.x * blockDim.x + threadIdx.x;
    int e0 = t * 4;
    if (e0 + 4 <= n_edges) {
        int4 d4 = *(const int4*)(dst + e0);
        atomicAdd(&deg[d4.x], 1);
        atomicAdd(&deg[d4.y], 1);
        atomicAdd(&deg[d4.z], 1);
        atomicAdd(&deg[d4.w], 1);
    } else {
        for (int e = e0; e < n_edges; e++) atomicAdd(&deg[dst[e]], 1);
    }
}

// ------------------------------------------- scan (padded to 8) + dinv ------
__global__ __launch_bounds__(256) void scan_phaseA(const int* __restrict__ deg,
                                                   float* __restrict__ dinv,
                                                   int* __restrict__ blocksum,
                                                   int N) {
    int i = blockIdx.x * 256 + threadIdx.x;
    int d = (i < N) ? deg[i] : 0;
    if (i < N) dinv[i] = rsqrtf((float)d + 1.0f);
    int v = (d + 7) & ~7;
#pragma unroll
    for (int off = 32; off > 0; off >>= 1) v += __shfl_down(v, off, 64);
    __shared__ int s[4];
    if ((threadIdx.x & 63) == 0) s[threadIdx.x >> 6] = v;
    __syncthreads();
    if (threadIdx.x == 0) blocksum[blockIdx.x] = s[0] + s[1] + s[2] + s[3];
}

__global__ __launch_bounds__(256) void scan_phaseC(const int* __restrict__ deg,
                                                   const int* __restrict__ blocksum,
                                                   int* __restrict__ rowptr,
                                                   int* __restrict__ cursor,
                                                   int N, int NB) {
    int t = threadIdx.x;
    int mine = (t < NB && t < blockIdx.x) ? blocksum[t] : 0;
#pragma unroll
    for (int off = 32; off > 0; off >>= 1) mine += __shfl_down(mine, off, 64);
    __shared__ int ps[4];
    if ((t & 63) == 0) ps[t >> 6] = mine;
    __syncthreads();
    int pref = ps[0] + ps[1] + ps[2] + ps[3];

    __shared__ int s[256];
    int i = blockIdx.x * 256 + t;
    int own = (i < N) ? (deg[i] + 7) & ~7 : 0;
    s[t] = own;
    __syncthreads();
#pragma unroll
    for (int off = 1; off < 256; off <<= 1) {
        int v = (t >= off) ? s[t - off] : 0;
        __syncthreads();
        s[t] += v;
        __syncthreads();
    }
    if (i < N) {
        int r = pref + s[t] - own;
        rowptr[i] = r;
        cursor[i] = r;
        if (i == N - 1) rowptr[N] = r + own;
    }
}

// ------------------------------------------------------------------ fill ----
__global__ void csr_fill(const int* __restrict__ src, const int* __restrict__ dst,
                         int* __restrict__ cursor,
                         unsigned short* __restrict__ csr_src, int n_edges) {
    int t = blockIdx.x * blockDim.x + threadIdx.x;
    int e0 = t * 8;
    if (e0 + 8 <= n_edges) {
        int4 da = *(const int4*)(dst + e0);
        int4 db = *(const int4*)(dst + e0 + 4);
        int4 sa = *(const int4*)(src + e0);
        int4 sb = *(const int4*)(src + e0 + 4);
        int p0 = atomicAdd(&cursor[da.x], 1);
        int p1 = atomicAdd(&cursor[da.y], 1);
        int p2 = atomicAdd(&cursor[da.z], 1);
        int p3 = atomicAdd(&cursor[da.w], 1);
        int p4 = atomicAdd(&cursor[db.x], 1);
        int p5 = atomicAdd(&cursor[db.y], 1);
        int p6 = atomicAdd(&cursor[db.z], 1);
        int p7 = atomicAdd(&cursor[db.w], 1);
        csr_src[p0] = (unsigned short)sa.x;
        csr_src[p1] = (unsigned short)sa.y;
        csr_src[p2] = (unsigned short)sa.z;
        csr_src[p3] = (unsigned short)sa.w;
        csr_src[p4] = (unsigned short)sb.x;
        csr_src[p5] = (unsigned short)sb.y;
        csr_src[p6] = (unsigned short)sb.z;
        csr_src[p7] = (unsigned short)sb.w;
    } else {
        for (int e = e0; e < n_edges; e++) {
            int p = atomicAdd(&cursor[dst[e]], 1);
            csr_src[p] = (unsigned short)src[e];
        }
    }
}

// ----------------------------------------------------------- weight prep ----
__global__ void swizzle_W(const float* __restrict__ W0, const float* __restrict__ W1,
                          const float* __restrict__ W2, unsigned short* __restrict__ Wz) {
    const float* W = (blockIdx.x == 0) ? W0 : (blockIdx.x == 1) ? W1 : W2;
    unsigned short* dst = Wz + blockIdx.x * HID * HID;
    for (int e = threadIdx.x; e < HID * HID; e += blockDim.x) {
        int k = e / HID, n = e % HID;
        int nt = n >> 4, kki = k >> 5, quad = (k >> 3) & 3, j = k & 7;
        int lane = (n & 15) | (quad << 4);
        dst[(((nt * 3 + kki) * 64 + lane) << 3) | j] = f32_to_bf16(W[e]);
    }
}

// ----------------------------------------------------- GEMM0 (f32 input) ----
// Reads dense f32 x; writes h' = (xW)*dinv in SLICED layout.
__global__ __launch_bounds__(256) void gemm0_f32(
    const float* __restrict__ X, const unsigned short* __restrict__ Wz,
    const float* __restrict__ dinv, unsigned short* __restrict__ Out, int Mtiles) {
    int wv = threadIdx.x >> 6;
    int lane = threadIdx.x & 63;
    int quad = lane >> 4;
    int mrow = lane & 15;
    int tt = blockIdx.x * 2 + (wv >> 1);
    int half = wv & 1;
    if (tt >= Mtiles) return;

    short8 bfrag[9];
    const short8* Wz8 = (const short8*)Wz;
#pragma unroll
    for (int f = 0; f < 9; f++) bfrag[f] = Wz8[(half * 9 + f) * 64 + lane];

    int m0 = tt * 16;
    const float* arow = X + (size_t)(m0 + mrow) * HID + quad * 8;
    short8 a[3];
#pragma unroll
    for (int kb = 0; kb < 3; kb++) {
        float4 u = *(const float4*)(arow + kb * 32);
        float4 v = *(const float4*)(arow + kb * 32 + 4);
        short8 t;
        t[0] = (short)f32_to_bf16(u.x); t[1] = (short)f32_to_bf16(u.y);
        t[2] = (short)f32_to_bf16(u.z); t[3] = (short)f32_to_bf16(u.w);
        t[4] = (short)f32_to_bf16(v.x); t[5] = (short)f32_to_bf16(v.y);
        t[6] = (short)f32_to_bf16(v.z); t[7] = (short)f32_to_bf16(v.w);
        a[kb] = t;
    }
    float dscale[4];
#pragma unroll
    for (int r = 0; r < 4; r++) dscale[r] = dinv[m0 + quad * 4 + r];
#pragma unroll
    for (int ntl = 0; ntl < 3; ntl++) {
        int nt = half * 3 + ntl;
        floatx4 c = {0.0f, 0.0f, 0.0f, 0.0f};
        c = __builtin_amdgcn_mfma_f32_16x16x32_bf16(a[0], bfrag[ntl * 3 + 0], c, 0, 0, 0);
        c = __builtin_amdgcn_mfma_f32_16x16x32_bf16(a[1], bfrag[ntl * 3 + 1], c, 0, 0, 0);
        c = __builtin_amdgcn_mfma_f32_16x16x32_bf16(a[2], bfrag[ntl * 3 + 2], c, 0, 0, 0);
        int f = nt * 16 + mrow;
        unsigned short* ocol = Out + (size_t)(f / 12) * NROWS * 12 + (f % 12);
#pragma unroll
        for (int r = 0; r < 4; r++)
            ocol[(size_t)(m0 + quad * 4 + r) * 12] = f32_to_bf16(c[r] * dscale[r]);
    }
}

// ------------------------------------------------------ GEMM (sliced A) -----
// Reads activations in sliced layout; writes h' = (aW)*dinv sliced.
__global__ __launch_bounds__(256) void gemm_sliced(
    const unsigned short* __restrict__ A, const unsigned short* __restrict__ Wz,
    const float* __restrict__ dinv, unsigned short* __restrict__ Out, int Mtiles) {
    int wv = threadIdx.x >> 6;
    int lane = threadIdx.x & 63;
    int quad = lane >> 4;
    int mrow = lane & 15;
    int tt = blockIdx.x * 2 + (wv >> 1);
    int half = wv & 1;
    if (tt >= Mtiles) return;

    short8 bfrag[9];
    const short8* Wz8 = (const short8*)Wz;
#pragma unroll
    for (int f = 0; f < 9; f++) bfrag[f] = Wz8[(half * 9 + f) * 64 + lane];

    int m0 = tt * 16;
    int m = m0 + mrow;
    short8 a[3];
#pragma unroll
    for (int kb = 0; kb < 3; kb++) {
        int c = quad * 8 + kb * 32;
        int c4 = c + 4;
        ushort4 lo = *(const ushort4*)(A + ((size_t)(c / 12) * NROWS + m) * 12 + (c % 12));
        ushort4 hi = *(const ushort4*)(A + ((size_t)(c4 / 12) * NROWS + m) * 12 + (c4 % 12));
        short8 t;
        t[0] = (short)lo.x; t[1] = (short)lo.y; t[2] = (short)lo.z; t[3] = (short)lo.w;
        t[4] = (short)hi.x; t[5] = (short)hi.y; t[6] = (short)hi.z; t[7] = (short)hi.w;
        a[kb] = t;
    }
    float dscale[4];
#pragma unroll
    for (int r = 0; r < 4; r++) dscale[r] = dinv[m0 + quad * 4 + r];
#pragma unroll
    for (int ntl = 0; ntl < 3; ntl++) {
        int nt = half * 3 + ntl;
        floatx4 c = {0.0f, 0.0f, 0.0f, 0.0f};
        c = __builtin_amdgcn_mfma_f32_16x16x32_bf16(a[0], bfrag[ntl * 3 + 0], c, 0, 0, 0);
        c = __builtin_amdgcn_mfma_f32_16x16x32_bf16(a[1], bfrag[ntl * 3 + 1], c, 0, 0, 0);
        c = __builtin_amdgcn_mfma_f32_16x16x32_bf16(a[2], bfrag[ntl * 3 + 2], c, 0, 0, 0);
        int f = nt * 16 + mrow;
        unsigned short* ocol = Out + (size_t)(f / 12) * NROWS * 12 + (f % 12);
#pragma unroll
        for (int r = 0; r < 4; r++)
            ocol[(size_t)(m0 + quad * 4 + r) * 12] = f32_to_bf16(c[r] * dscale[r]);
    }
}

// ------------------------------------------------- XCD-local sliced gather --
// Slice s = blockIdx%8 (round-robin -> one slice per XCD, 1.2 MB, L2-resident).
// Wave = 21 subgroups x 3 lanes; subgroup owns one node, lane owns 4 features.
__global__ __launch_bounds__(256) void gather_sliced(
    const unsigned short* __restrict__ h, const int* __restrict__ rowptr,
    const unsigned short* __restrict__ csr, const float* __restrict__ dinv,
    const float* __restrict__ bias, unsigned short* __restrict__ outa,
    int N, int do_relu) {
    int s = blockIdx.x & 7;
    int tile = blockIdx.x >> 3;
    int wv = threadIdx.x >> 6;
    int lane = threadIdx.x & 63;
    int sub = lane / 3;
    int r = lane - sub * 3;
    if (sub >= 21) return;  // lane 63 idle
    int n = tile * NPB + wv * 21 + sub;
    if (n >= N) return;

    const unsigned short* hs = h + (size_t)s * NROWS * 12;
    int fo = r * 4;
    int start = rowptr[n];
    int end = rowptr[n + 1];  // 8-aligned; pads hit zeroed sentinel row
    float di = dinv[n];

    ushort4 hv = *(const ushort4*)(hs + (size_t)n * 12 + fo);
    float a0 = bf16_to_f32(hv.x), a1 = bf16_to_f32(hv.y);
    float a2 = bf16_to_f32(hv.z), a3 = bf16_to_f32(hv.w);

    for (int i = start; i < end; i += 8) {
        ushort8v iv = *(const ushort8v*)(csr + i);
        ushort4 v0 = *(const ushort4*)(hs + (size_t)iv[0] * 12 + fo);
        ushort4 v1 = *(const ushort4*)(hs + (size_t)iv[1] * 12 + fo);
        ushort4 v2 = *(const ushort4*)(hs + (size_t)iv[2] * 12 + fo);
        ushort4 v3 = *(const ushort4*)(hs + (size_t)iv[3] * 12 + fo);
        ushort4 v4 = *(const ushort4*)(hs + (size_t)iv[4] * 12 + fo);
        ushort4 v5 = *(const ushort4*)(hs + (size_t)iv[5] * 12 + fo);
        ushort4 v6 = *(const ushort4*)(hs + (size_t)iv[6] * 12 + fo);
        ushort4 v7 = *(const ushort4*)(hs + (size_t)iv[7] * 12 + fo);
        a0 += bf16_to_f32(v0.x) + bf16_to_f32(v1.x) + bf16_to_f32(v2.x) +
              bf16_to_f32(v3.x) + bf16_to_f32(v4.x) + bf16_to_f32(v5.x) +
              bf16_to_f32(v6.x) + bf16_to_f32(v7.x);
        a1 += bf16_to_f32(v0.y) + bf16_to_f32(v1.y) + bf16_to_f32(v2.y) +
              bf16_to_f32(v3.y) + bf16_to_f32(v4.y) + bf16_to_f32(v5.y) +
              bf16_to_f32(v6.y) + bf16_to_f32(v7.y);
        a2 += bf16_to_f32(v0.z) + bf16_to_f32(v1.z) + bf16_to_f32(v2.z) +
              bf16_to_f32(v3.z) + bf16_to_f32(v4.z) + bf16_to_f32(v5.z) +
              bf16_to_f32(v6.z) + bf16_to_f32(v7.z);
        a3 += bf16_to_f32(v0.w) + bf16_to_f32(v1.w) + bf16_to_f32(v2.w) +
              bf16_to_f32(v3.w) + bf16_to_f32(v4.w) + bf16_to_f32(v5.w) +
              bf16_to_f32(v6.w) + bf16_to_f32(v7.w);
    }
    float4 bb = *(const float4*)(bias + s * 12 + fo);
    a0 = a0 * di + bb.x;
    a1 = a1 * di + bb.y;
    a2 = a2 * di + bb.z;
    a3 = a3 * di + bb.w;
    if (do_relu) {
        a0 = fmaxf(a0, 0.0f);
        a1 = fmaxf(a1, 0.0f);
        a2 = fmaxf(a2, 0.0f);
        a3 = fmaxf(a3, 0.0f);
    }
    ushort4 o;
    o.x = f32_to_bf16(a0);
    o.y = f32_to_bf16(a1);
    o.z = f32_to_bf16(a2);
    o.w = f32_to_bf16(a3);
    *(ushort4*)(outa + (size_t)s * NROWS * 12 + (size_t)n * 12 + fo) = o;
}

// ---------------------------------------------------------------- pooling ---
// Reads final activations in sliced layout; 32-node run-length chunks.
#define PCH 32
__global__ __launch_bounds__(96) void pool_sliced(
    const unsigned short* __restrict__ a3, const int* __restrict__ batch,
    float* __restrict__ sums, float* __restrict__ cnts, int N) {
    int n0 = blockIdx.x * PCH;
    if (n0 >= N) return;
    int f = threadIdx.x;
    const unsigned short* col = a3 + (size_t)(f / 12) * NROWS * 12 + (f % 12);
    int nend = min(n0 + PCH, N);
    int gfirst = batch[n0];
    int glast = batch[nend - 1];
    if (gfirst == glast) {
        float acc = 0.0f;
#pragma unroll 8
        for (int n = n0; n < nend; n++) acc += bf16_to_f32(col[(size_t)n * 12]);
        atomicAdd(&sums[gfirst * HID + f], acc);
        if (f == 0) atomicAdd(&cnts[gfirst], (float)(nend - n0));
        return;
    }
    int g_cur = gfirst;
    float acc = 0.0f, cacc = 0.0f;
    for (int n = n0; n < nend; n++) {
        int g = batch[n];
        if (g != g_cur) {
            atomicAdd(&sums[g_cur * HID + f], acc);
            if (f == 0) atomicAdd(&cnts[g_cur], cacc);
            acc = 0.0f;
            cacc = 0.0f;
            g_cur = g;
        }
        acc += bf16_to_f32(col[(size_t)n * 12]);
        cacc += 1.0f;
    }
    atomicAdd(&sums[g_cur * HID + f], acc);
    if (f == 0) atomicAdd(&cnts[g_cur], cacc);
}

// ---------------------------------------------------------------- head ------
__global__ __launch_bounds__(640) void final_kernel(
    const float* __restrict__ sums, const float* __restrict__ cnts,
    const float* __restrict__ Wlin, const float* __restrict__ blin,
    float* __restrict__ out) {
    int t = threadIdx.x;
    if (t >= NGRAPHS * 10) return;
    int g = t / 10;
    int c = t % 10;
    float denom = fmaxf(cnts[g], 1.0f);
    float acc = blin[c];
#pragma unroll
    for (int f = 0; f < HID; f++)
        acc += (sums[g * HID + f] / denom) * Wlin[f * 10 + c];
    out[t] = acc;
}

// ---------------------------------------------------------------- launch ----
extern "C" void kernel_launch(void* const* d_in, const int* in_sizes, int n_in,
                              void* d_out, int out_size, void* d_ws,
                              size_t ws_size, hipStream_t stream) {
    const float* x = (const float*)d_in[0];
    const int* edge = (const int*)d_in[1];
    const int* batch = (const int*)d_in[2];
    const float* W[3] = {(const float*)d_in[3], (const float*)d_in[5],
                         (const float*)d_in[7]};
    const float* B[3] = {(const float*)d_in[4], (const float*)d_in[6],
                         (const float*)d_in[8]};
    const float* Wlin = (const float*)d_in[9];
    const float* blin = (const float*)d_in[10];
    float* out = (float*)d_out;

    int N = in_sizes[0] / HID;  // 50000
    int E = in_sizes[1] / 2;    // 800000
    const int* src = edge;
    const int* dst = edge + E;
    int NB = (N + 255) / 256;   // 196

    char* ws = (char*)d_ws;
    size_t off = 0;
    auto alloc = [&](size_t bytes) {
        void* p = ws + off;
        off += (bytes + 255) & ~(size_t)255;
        return p;
    };
    int* deg = (int*)alloc((size_t)N * 4);
    float* dinv = (float*)alloc((size_t)N * 4);
    int* rowptr = (int*)alloc(((size_t)N + 1) * 4);
    int* cursor = (int*)alloc((size_t)N * 4);
    int* blocksum = (int*)alloc((size_t)NB * 4);
    size_t csr_cap = (size_t)E + 8 * (size_t)N;
    unsigned short* csr_src = (unsigned short*)alloc(csr_cap * 2 + 64);
    unsigned short* Wz = (unsigned short*)alloc(3 * HID * HID * 2);
    unsigned short* bufA = (unsigned short*)alloc((size_t)NROWS * HID * 2);
    unsigned short* bufB = (unsigned short*)alloc((size_t)NROWS * HID * 2);
    float* psum = (float*)alloc((NGRAPHS * HID + NGRAPHS) * 4);
    float* pcnt = psum + NGRAPHS * HID;

    // --- CSR build + weight prep ---
    hipMemsetAsync(csr_src, 0xC3, csr_cap * 2, stream);  // pads -> sentinel row
    init_kernel<<<NB, 256, 0, stream>>>(deg, psum, bufA, bufB, N);
    deg_kernel<<<(E / 4 + 255) / 256, 256, 0, stream>>>(dst, deg, E);
    scan_phaseA<<<NB, 256, 0, stream>>>(deg, dinv, blocksum, N);
    scan_phaseC<<<NB, 256, 0, stream>>>(deg, blocksum, rowptr, cursor, N, NB);
    csr_fill<<<(E / 8 + 255) / 256, 256, 0, stream>>>(src, dst, cursor, csr_src, E);
    swizzle_W<<<3, 256, 0, stream>>>(W[0], W[1], W[2], Wz);

    int Mtiles = (N + 15) / 16;            // 3125
    int grid2 = (Mtiles + 1) / 2;          // 1563
    int gtiles = (N + NPB - 1) / NPB;      // 596
    int ggrid = 8 * gtiles;                // 4768: slice = blockIdx % 8
    int pgrid = (N + PCH - 1) / PCH;       // 1563

    gemm0_f32<<<grid2, 256, 0, stream>>>(x, Wz, dinv, bufA, Mtiles);
    gather_sliced<<<ggrid, 256, 0, stream>>>(bufA, rowptr, csr_src, dinv, B[0],
                                             bufB, N, 1);
    gemm_sliced<<<grid2, 256, 0, stream>>>(bufB, Wz + 1 * HID * HID, dinv, bufA,
                                           Mtiles);
    gather_sliced<<<ggrid, 256, 0, stream>>>(bufA, rowptr, csr_src, dinv, B[1],
                                             bufB, N, 1);
    gemm_sliced<<<grid2, 256, 0, stream>>>(bufB, Wz + 2 * HID * HID, dinv, bufA,
                                           Mtiles);
    gather_sliced<<<ggrid, 256, 0, stream>>>(bufA, rowptr, csr_src, dinv, B[2],
                                             bufB, N, 0);
    pool_sliced<<<pgrid, 96, 0, stream>>>(bufB, batch, psum, pcnt, N);
    final_kernel<<<1, 640, 0, stream>>>(psum, pcnt, Wlin, blin, out);
}